// Round 4
// baseline (870.535 us; speedup 1.0000x reference)
//
#include <hip/hip_runtime.h>
#include <hip/hip_bf16.h>

typedef _Float16 f16x8 __attribute__((ext_vector_type(8)));
typedef _Float16 f16x4 __attribute__((ext_vector_type(4)));
typedef float f32x4 __attribute__((ext_vector_type(4)));

#define B_   16
#define NL   256
#define NP   2048
#define NH   8
#define PSPLIT 4
#define PCHUNK (NP / PSPLIT)   // 512

static __device__ __forceinline__ f32x4 mfma16(f16x8 a, f16x8 b, f32x4 c) {
  return __builtin_amdgcn_mfma_f32_16x16x32_f16(a, b, c, 0, 0, 0);
}

// ---------------- projection: x[b][n][64] @ W[64][512] + bias, relu ----------------
__global__ __launch_bounds__(256) void proj_kernel(
    const float* __restrict__ x, const float* __restrict__ W, const float* __restrict__ bias,
    _Float16* __restrict__ outA, _Float16* __restrict__ outB, int N, int mode)
{
  __shared__ float xt[64][68];
  const int t = threadIdx.x;
  const int n0 = blockIdx.x * 64;
  const int h  = blockIdx.y;
  const int b  = blockIdx.z;

  const float* xp = x + ((size_t)b * N + n0) * 64;
#pragma unroll
  for (int i = 0; i < 4; ++i) {
    int flat = (i * 256 + t) * 4;
    f32x4 v = *(const f32x4*)(xp + flat);
    *(f32x4*)&xt[flat >> 6][flat & 63] = v;
  }
  __syncthreads();

  const int nb = (t >> 4) * 4;
  const int db = (t & 15) * 4;

  float acc[4][4];
#pragma unroll
  for (int i = 0; i < 4; ++i)
#pragma unroll
    for (int j = 0; j < 4; ++j) acc[i][j] = bias[h * 64 + db + j];

  const float* wp = W + h * 64 + db;
#pragma unroll 8
  for (int k = 0; k < 64; ++k) {
    f32x4 wq = *(const f32x4*)(wp + (size_t)k * 512);
    float a0 = xt[nb + 0][k], a1 = xt[nb + 1][k], a2 = xt[nb + 2][k], a3 = xt[nb + 3][k];
#pragma unroll
    for (int j = 0; j < 4; ++j) {
      acc[0][j] += a0 * wq[j];
      acc[1][j] += a1 * wq[j];
      acc[2][j] += a2 * wq[j];
      acc[3][j] += a3 * wq[j];
    }
  }

  if (mode == 0) {
#pragma unroll
    for (int i = 0; i < 4; ++i) {
      f16x4 hv, lv;
#pragma unroll
      for (int j = 0; j < 4; ++j) {
        float v = fmaxf(acc[i][j], 0.f);
        _Float16 hi = (_Float16)v;
        hv[j] = hi;
        lv[j] = (_Float16)((v - (float)hi) * 2048.0f);
      }
      size_t idx = (((size_t)b * NH + h) * N + n0 + nb + i) * 64 + db;
      *(f16x4*)(outA + idx) = hv;
      *(f16x4*)(outB + idx) = lv;
    }
  } else {
#pragma unroll
    for (int j = 0; j < 4; ++j) {
      f16x4 tv;
#pragma unroll
      for (int i = 0; i < 4; ++i) tv[i] = (_Float16)fmaxf(acc[i][j], 0.f);
      size_t idx = (((size_t)b * NH + h) * 64 + db + j) * N + n0 + nb;
      *(f16x4*)(outA + idx) = tv;
    }
  }
}

// ---------------- flash pass (head-fused, P-split, pipelined) ----------------
// grid: x = sp + PSPLIT*b (64), y = lt (16) => blocks sharing a p1-chunk colocate on an XCD
__global__ __launch_bounds__(512, 4) void flash_l3_kernel(
    const _Float16* __restrict__ l1h, const _Float16* __restrict__ l1l,
    const _Float16* __restrict__ p1h, const _Float16* __restrict__ p1l,
    const _Float16* __restrict__ p2t, const float* __restrict__ dist,
    float* __restrict__ l3p, float* __restrict__ mpart, float* __restrict__ spart)
{
  const int sb = blockIdx.x;
  const int sp = sb & (PSPLIT - 1);
  const int b  = sb >> 2;
  const int lt = blockIdx.y;
  const int t  = threadIdx.x;
  const int h    = t >> 6;
  const int lane = t & 63;
  const int g = lane >> 4, c = lane & 15;
  const int l0 = lt * 16;
  const int bh = b * NH + h;
  const int NT = PCHUNK / 64;           // 8

  __shared__ float distT[2][64][20];    // [buf][p-local][l-local]
  __shared__ _Float16 P[NH][16][72];    // per-wave scratch (no barrier)

  const size_t l1off = ((size_t)bh * NL + l0 + c) * 64;
  f16x8 aLh[2], aLl[2];
  aLh[0] = *(const f16x8*)(l1h + l1off + g * 8);
  aLh[1] = *(const f16x8*)(l1h + l1off + 32 + g * 8);
  aLl[0] = *(const f16x8*)(l1l + l1off + g * 8);
  aLl[1] = *(const f16x8*)(l1l + l1off + 32 + g * 8);

  f32x4 accO[4];
#pragma unroll
  for (int dt = 0; dt < 4; ++dt) accO[dt] = (f32x4){0.f, 0.f, 0.f, 0.f};
  float m_r[4] = {-INFINITY, -INFINITY, -INFINITY, -INFINITY};
  float s_r[4] = {0.f, 0.f, 0.f, 0.f};

  const float* dbase = dist + ((size_t)b * NL + l0) * NP + sp * PCHUNK;
  const _Float16* p1hb = p1h + ((size_t)bh * NP + sp * PCHUNK) * 64;
  const _Float16* p1lb = p1l + ((size_t)bh * NP + sp * PCHUNK) * 64;
  const _Float16* p2tb = p2t + (size_t)bh * 64 * NP + sp * PCHUNK;
  const float fh = (float)h, fh3 = fh + 3.0f;

  const int dl_p = t & 63;              // coop dist-load: p-local
  const int dl_l = t >> 6;              // coop dist-load: l rows dl_l, dl_l+8

  // prologue: stage dist tile 0
  {
    float dv0 = dbase[(size_t)dl_l * NP + dl_p];
    float dv1 = dbase[(size_t)(dl_l + 8) * NP + dl_p];
    distT[0][dl_p][dl_l]     = dv0;
    distT[0][dl_p][dl_l + 8] = dv1;
  }

  for (int it = 0; it < NT; ++it) {
    const int P0 = it * 64;
    const int cur = it & 1;
    __syncthreads();                    // distT[cur] ready; distT[cur^1] free

    // prefetch next tile's dist into regs (hides a full tile of compute)
    float nv0 = 0.f, nv1 = 0.f;
    if (it + 1 < NT) {
      nv0 = dbase[(size_t)dl_l * NP + P0 + 64 + dl_p];
      nv1 = dbase[(size_t)(dl_l + 8) * NP + P0 + 64 + dl_p];
    }

    // hoist PV operand loads (no LDS dependency; land during QK+softmax)
    f16x8 v0[4], v1[4];
#pragma unroll
    for (int dt = 0; dt < 4; ++dt) {
      const _Float16* vp = p2tb + (size_t)(dt * 16 + c) * NP + P0 + g * 8;
      v0[dt] = *(const f16x8*)(vp);
      v1[dt] = *(const f16x8*)(vp + 32);
    }

    float mev[4][4];
    float cmax[4] = {-INFINITY, -INFINITY, -INFINITY, -INFINITY};
#pragma unroll
    for (int s = 0; s < 4; ++s) {
      const _Float16* ph = p1hb + (size_t)(P0 + s * 16 + c) * 64;
      const _Float16* pl = p1lb + (size_t)(P0 + s * 16 + c) * 64;
      f16x8 bh0 = *(const f16x8*)(ph + g * 8);
      f16x8 bh1 = *(const f16x8*)(ph + 32 + g * 8);
      f16x8 bl0 = *(const f16x8*)(pl + g * 8);
      f16x8 bl1 = *(const f16x8*)(pl + 32 + g * 8);
      f32x4 e  = (f32x4){0.f, 0.f, 0.f, 0.f};
      f32x4 ec = (f32x4){0.f, 0.f, 0.f, 0.f};
      __builtin_amdgcn_s_setprio(1);
      e  = mfma16(aLh[0], bh0, e);  e  = mfma16(aLh[1], bh1, e);
      ec = mfma16(aLh[0], bl0, ec); ec = mfma16(aLh[1], bl1, ec);
      ec = mfma16(aLl[0], bh0, ec); ec = mfma16(aLl[1], bh1, ec);
      __builtin_amdgcn_s_setprio(0);
      f32x4 dq = *(const f32x4*)&distT[cur][s * 16 + c][g * 4];
#pragma unroll
      for (int r = 0; r < 4; ++r) {
        float dv = dq[r];
        float ev = (e[r] + ec[r] * (1.0f / 2048.0f)) * 0.125f;
        bool cond = (h < 7) ? (dv > fh && dv <= fh3) : (dv > 7.0f);
        float m = cond ? ev * __builtin_amdgcn_rcpf(dv) : 0.0f;
        mev[s][r] = m;
        cmax[r] = fmaxf(cmax[r], m);
      }
    }
#pragma unroll
    for (int mask = 1; mask < 16; mask <<= 1)
#pragma unroll
      for (int r = 0; r < 4; ++r)
        cmax[r] = fmaxf(cmax[r], __shfl_xor(cmax[r], mask, 64));

#pragma unroll
    for (int r = 0; r < 4; ++r) {
      float mn  = fmaxf(m_r[r], cmax[r]);
      float fac = __expf(m_r[r] - mn);
      m_r[r] = mn;
      float ss = 0.f;
#pragma unroll
      for (int s = 0; s < 4; ++s) {
        float pv = __expf(mev[s][r] - mn);
        ss += pv;
        P[h][g * 4 + r][s * 16 + c] = (_Float16)pv;
      }
      s_r[r] = s_r[r] * fac + ss;
#pragma unroll
      for (int dt = 0; dt < 4; ++dt) accO[dt][r] *= fac;
    }
    // PV (per-wave LDS dep; compiler inserts lgkmcnt)
    {
      f16x8 aP0 = *(const f16x8*)&P[h][c][g * 8];
      f16x8 aP1 = *(const f16x8*)&P[h][c][32 + g * 8];
      __builtin_amdgcn_s_setprio(1);
#pragma unroll
      for (int dt = 0; dt < 4; ++dt) accO[dt] = mfma16(aP0, v0[dt], accO[dt]);
#pragma unroll
      for (int dt = 0; dt < 4; ++dt) accO[dt] = mfma16(aP1, v1[dt], accO[dt]);
      __builtin_amdgcn_s_setprio(0);
    }
    // stage next dist tile into the alternate buffer
    if (it + 1 < NT) {
      distT[cur ^ 1][dl_p][dl_l]     = nv0;
      distT[cur ^ 1][dl_p][dl_l + 8] = nv1;
    }
  }

#pragma unroll
  for (int mask = 1; mask < 16; mask <<= 1)
#pragma unroll
    for (int r = 0; r < 4; ++r) s_r[r] += __shfl_xor(s_r[r], mask, 64);

  float* lp = l3p + (size_t)sp * B_ * NL * 512;
#pragma unroll
  for (int dt = 0; dt < 4; ++dt)
#pragma unroll
    for (int r = 0; r < 4; ++r)
      lp[((size_t)b * NL + l0 + g * 4 + r) * 512 + h * 64 + dt * 16 + c] = accO[dt][r];

  if (c == 0) {
#pragma unroll
    for (int r = 0; r < 4; ++r) {
      size_t li = (size_t)sp * B_ * NH * NL + (size_t)bh * NL + l0 + g * 4 + r;
      mpart[li] = m_r[r];
      spart[li] = s_r[r];
    }
  }
}

// ---------------- merge split-P partials ----------------
__global__ __launch_bounds__(256) void merge_l3_kernel(
    const float* __restrict__ l3p, const float* __restrict__ mpart, const float* __restrict__ spart,
    float* __restrict__ l3c, float* __restrict__ mrow, float* __restrict__ rsrow)
{
  const int row = blockIdx.x * 4 + (threadIdx.x >> 6);
  const int d   = threadIdx.x & 63;
  const int l   = row & (NL - 1);
  const int bh  = row >> 8;
  const int b = bh >> 3, h = bh & 7;
  const size_t srow = (size_t)B_ * NH * NL;

  float mi[PSPLIT], si[PSPLIT];
  float M = -INFINITY;
#pragma unroll
  for (int i = 0; i < PSPLIT; ++i) {
    mi[i] = mpart[(size_t)i * srow + row];
    si[i] = spart[(size_t)i * srow + row];
    M = fmaxf(M, mi[i]);
  }
  const float* lp = l3p + ((size_t)b * NL + l) * 512 + h * 64 + d;
  float S = 0.f, o = 0.f;
#pragma unroll
  for (int i = 0; i < PSPLIT; ++i) {
    float w = __expf(mi[i] - M);
    S += si[i] * w;
    o += lp[(size_t)i * B_ * NL * 512] * w;
  }
  float rs = 1.0f / S;
  l3c[((size_t)b * NL + l) * 512 + h * 64 + d] = o * rs;
  if (d == 0) { mrow[row] = M; rsrow[row] = rs; }
}

// ---------------- pass 2 (head-fused, pipelined): p3 = att^T @ l2 ----------------
// grid: x = b (16), y = pt (128): blocks sharing a batch's l1 colocate per XCD
__global__ __launch_bounds__(512, 4) void p3_kernel(
    const _Float16* __restrict__ p1h, const _Float16* __restrict__ p1l,
    const _Float16* __restrict__ l1h, const _Float16* __restrict__ l1l,
    const _Float16* __restrict__ l2t, const float* __restrict__ dist,
    const float* __restrict__ mrow, const float* __restrict__ rsrow,
    float* __restrict__ p3c)
{
  const int b  = blockIdx.x;
  const int pt = blockIdx.y;
  const int t  = threadIdx.x;
  const int h    = t >> 6;
  const int lane = t & 63;
  const int g = lane >> 4, c = lane & 15;
  const int p0 = pt * 16;
  const int bh = b * NH + h;
  const int NT = NL / 32;               // 8

  __shared__ float distT[2][32][20];    // [buf][l-local][p-local]
  __shared__ _Float16 PT[NH][16][40];   // per-wave

  const size_t poff = ((size_t)bh * NP + p0 + c) * 64;
  f16x8 aPh[2], aPl[2];
  aPh[0] = *(const f16x8*)(p1h + poff + g * 8);
  aPh[1] = *(const f16x8*)(p1h + poff + 32 + g * 8);
  aPl[0] = *(const f16x8*)(p1l + poff + g * 8);
  aPl[1] = *(const f16x8*)(p1l + poff + 32 + g * 8);

  f32x4 acc[4];
#pragma unroll
  for (int dt = 0; dt < 4; ++dt) acc[dt] = (f32x4){0.f, 0.f, 0.f, 0.f};

  const float* db_ = dist + (size_t)b * NL * NP + p0;
  const _Float16* l1hb = l1h + (size_t)bh * NL * 64;
  const _Float16* l1lb = l1l + (size_t)bh * NL * 64;
  const _Float16* l2tb = l2t + (size_t)bh * 64 * NL;
  const float* mb = mrow + (size_t)bh * NL;
  const float* rb = rsrow + (size_t)bh * NL;
  const float fh = (float)h, fh3 = fh + 3.0f;

  const int dl_l = t >> 4;              // 0..31
  const int dl_p = t & 15;

  // prologue: stage dist tile 0
  distT[0][dl_l][dl_p] = db_[(size_t)dl_l * NP + dl_p];

  for (int it = 0; it < NT; ++it) {
    const int lc = it * 32;
    const int cur = it & 1;
    __syncthreads();

    float nv = 0.f;
    if (it + 1 < NT)
      nv = db_[(size_t)(lc + 32 + dl_l) * NP + dl_p];

    // hoist PV operands
    f16x8 bV[4];
#pragma unroll
    for (int dt = 0; dt < 4; ++dt)
      bV[dt] = *(const f16x8*)(l2tb + (size_t)(dt * 16 + c) * NL + lc + g * 8);

#pragma unroll
    for (int s = 0; s < 2; ++s) {
      const int l = lc + s * 16 + c;
      const _Float16* lhp = l1hb + (size_t)l * 64;
      const _Float16* llp = l1lb + (size_t)l * 64;
      f16x8 bh0 = *(const f16x8*)(lhp + g * 8);
      f16x8 bh1 = *(const f16x8*)(lhp + 32 + g * 8);
      f16x8 bl0 = *(const f16x8*)(llp + g * 8);
      f16x8 bl1 = *(const f16x8*)(llp + 32 + g * 8);
      f32x4 e  = (f32x4){0.f, 0.f, 0.f, 0.f};
      f32x4 ec = (f32x4){0.f, 0.f, 0.f, 0.f};
      __builtin_amdgcn_s_setprio(1);
      e  = mfma16(aPh[0], bh0, e);  e  = mfma16(aPh[1], bh1, e);
      ec = mfma16(aPh[0], bl0, ec); ec = mfma16(aPh[1], bl1, ec);
      ec = mfma16(aPl[0], bh0, ec); ec = mfma16(aPl[1], bh1, ec);
      __builtin_amdgcn_s_setprio(0);
      float ml = mb[l], rl = rb[l];
      f32x4 dq = *(const f32x4*)&distT[cur][s * 16 + c][g * 4];
#pragma unroll
      for (int r = 0; r < 4; ++r) {
        float ev = (e[r] + ec[r] * (1.0f / 2048.0f)) * 0.125f;
        float dvv = dq[r];
        bool cond = (h < 7) ? (dvv > fh && dvv <= fh3) : (dvv > 7.0f);
        float m = cond ? ev * __builtin_amdgcn_rcpf(dvv) : 0.0f;
        float att = __expf(m - ml) * rl;
        PT[h][g * 4 + r][s * 16 + c] = (_Float16)att;
      }
    }
    {
      f16x8 aA = *(const f16x8*)&PT[h][c][g * 8];
      __builtin_amdgcn_s_setprio(1);
#pragma unroll
      for (int dt = 0; dt < 4; ++dt) acc[dt] = mfma16(aA, bV[dt], acc[dt]);
      __builtin_amdgcn_s_setprio(0);
    }
    if (it + 1 < NT)
      distT[cur ^ 1][dl_l][dl_p] = nv;
  }

#pragma unroll
  for (int dt = 0; dt < 4; ++dt)
#pragma unroll
    for (int r = 0; r < 4; ++r)
      p3c[((size_t)b * NP + p0 + g * 4 + r) * 512 + h * 64 + dt * 16 + c] = acc[dt][r];
}

// ---------------- FC chain ----------------
__global__ __launch_bounds__(256) void fc_out_kernel(
    const float* __restrict__ x3c, const float* __restrict__ xbase,
    const float* __restrict__ wA, const float* __restrict__ bA,
    const float* __restrict__ wB, const float* __restrict__ bB,
    float* __restrict__ out, int N, int out_off)
{
  __shared__ float xl[16][520];
  __shared__ float t1[16][68];
  __shared__ float xb[16][68];
  const int t = threadIdx.x;
  const int row0 = blockIdx.x * 16;

  const float* xp = x3c + (size_t)row0 * 512;
#pragma unroll
  for (int i = 0; i < 8; ++i) {
    int flat = (i * 256 + t) * 4;
    f32x4 v = *(const f32x4*)(xp + flat);
    *(f32x4*)&xl[flat >> 9][flat & 511] = v;
  }
  {
    const float* bp = xbase + (size_t)row0 * 64;
    int flat = t * 4;
    f32x4 v = *(const f32x4*)(bp + flat);
    *(f32x4*)&xb[flat >> 6][flat & 63] = v;
  }
  __syncthreads();

  const int r  = t >> 4;
  const int c4 = (t & 15) * 4;

  float acc[4];
#pragma unroll
  for (int j = 0; j < 4; ++j) acc[j] = bA[c4 + j];
  for (int k4 = 0; k4 < 128; ++k4) {
    f32x4 xq = *(const f32x4*)&xl[r][k4 * 4];
#pragma unroll
    for (int kk = 0; kk < 4; ++kk) {
      f32x4 wq = *(const f32x4*)(wA + (size_t)(k4 * 4 + kk) * 64 + c4);
#pragma unroll
      for (int j = 0; j < 4; ++j) acc[j] += xq[kk] * wq[j];
    }
  }
#pragma unroll
  for (int j = 0; j < 4; ++j) t1[r][c4 + j] = acc[j];
  __syncthreads();

  float a2[4];
#pragma unroll
  for (int j = 0; j < 4; ++j) a2[j] = bB[c4 + j];
  for (int k4 = 0; k4 < 32; ++k4) {
    f32x4 xq = (k4 < 16) ? *(const f32x4*)&t1[r][k4 * 4]
                         : *(const f32x4*)&xb[r][k4 * 4 - 64];
#pragma unroll
    for (int kk = 0; kk < 4; ++kk) {
      f32x4 wq = *(const f32x4*)(wB + (size_t)(k4 * 4 + kk) * 64 + c4);
#pragma unroll
      for (int j = 0; j < 4; ++j) a2[j] += xq[kk] * wq[j];
    }
  }
  const int row = row0 + r;
  const int b = row / N, n = row % N;
  f32x4 o;
#pragma unroll
  for (int j = 0; j < 4; ++j) o[j] = fmaxf(a2[j], 0.f);
  *(f32x4*)(out + (((size_t)b * (NL + NP)) + out_off + n) * 64 + c4) = o;
}

extern "C" void kernel_launch(void* const* d_in, const int* in_sizes, int n_in,
                              void* d_out, int out_size, void* d_ws, size_t ws_size,
                              hipStream_t stream)
{
  const float* ligand = (const float*)d_in[0];
  const float* prot   = (const float*)d_in[1];
  const float* dist   = (const float*)d_in[2];
  const float* w_l1   = (const float*)d_in[3];
  const float* b_l1   = (const float*)d_in[4];
  const float* w_l2   = (const float*)d_in[5];
  const float* b_l2   = (const float*)d_in[6];
  const float* w_p1   = (const float*)d_in[7];
  const float* b_p1   = (const float*)d_in[8];
  const float* w_p2   = (const float*)d_in[9];
  const float* b_p2   = (const float*)d_in[10];
  const float* fc11_w = (const float*)d_in[11];
  const float* fc11_b = (const float*)d_in[12];
  const float* fc12_w = (const float*)d_in[13];
  const float* fc12_b = (const float*)d_in[14];
  const float* fc21_w = (const float*)d_in[15];
  const float* fc21_b = (const float*)d_in[16];
  const float* fc22_w = (const float*)d_in[17];
  const float* fc22_b = (const float*)d_in[18];
  float* out = (float*)d_out;

  char* ws = (char*)d_ws;
  size_t off = 0;
  auto alloc = [&](size_t bytes) -> void* {
    void* p = ws + off;
    off += (bytes + 255) & ~(size_t)255;
    return p;
  };
  const size_t L1E = (size_t)B_ * NH * NL * 64;
  const size_t P1E = (size_t)B_ * NH * NP * 64;
  _Float16* l1h = (_Float16*)alloc(L1E * 2);
  _Float16* l1l = (_Float16*)alloc(L1E * 2);
  _Float16* p1h = (_Float16*)alloc(P1E * 2);
  _Float16* p1l = (_Float16*)alloc(P1E * 2);
  _Float16* l2t = (_Float16*)alloc(L1E * 2);
  _Float16* p2t = (_Float16*)alloc(P1E * 2);
  float* mrow  = (float*)alloc((size_t)B_ * NH * NL * 4);
  float* rsrow = (float*)alloc((size_t)B_ * NH * NL * 4);
  float* mpart = (float*)alloc((size_t)PSPLIT * B_ * NH * NL * 4);
  float* spart = (float*)alloc((size_t)PSPLIT * B_ * NH * NL * 4);
  float* l3c = (float*)alloc((size_t)B_ * NL * 512 * 4);
  float* p3c = (float*)alloc((size_t)B_ * NP * 512 * 4);
  float* l3p = p3c;   // alias: l3 partials are dead before p3_kernel writes p3c

  proj_kernel<<<dim3(NL / 64, NH, B_), 256, 0, stream>>>(ligand, w_l1, b_l1, l1h, l1l, NL, 0);
  proj_kernel<<<dim3(NL / 64, NH, B_), 256, 0, stream>>>(ligand, w_l2, b_l2, l2t, nullptr, NL, 1);
  proj_kernel<<<dim3(NP / 64, NH, B_), 256, 0, stream>>>(prot, w_p1, b_p1, p1h, p1l, NP, 0);
  proj_kernel<<<dim3(NP / 64, NH, B_), 256, 0, stream>>>(prot, w_p2, b_p2, p2t, nullptr, NP, 1);

  flash_l3_kernel<<<dim3(PSPLIT * B_, NL / 16), 512, 0, stream>>>(
      l1h, l1l, p1h, p1l, p2t, dist, l3p, mpart, spart);
  merge_l3_kernel<<<(B_ * NH * NL) / 4, 256, 0, stream>>>(l3p, mpart, spart, l3c, mrow, rsrow);
  p3_kernel<<<dim3(B_, NP / 16), 512, 0, stream>>>(p1h, p1l, l1h, l1l, l2t, dist,
                                                   mrow, rsrow, p3c);

  fc_out_kernel<<<(B_ * NL) / 16, 256, 0, stream>>>(l3c, ligand, fc11_w, fc11_b,
                                                    fc12_w, fc12_b, out, NL, 0);
  fc_out_kernel<<<(B_ * NP) / 16, 256, 0, stream>>>(p3c, prot, fc21_w, fc21_b,
                                                    fc22_w, fc22_b, out, NP, NL);
}

// Round 5
// 799.144 us; speedup vs baseline: 1.0893x; 1.0893x over previous
//
#include <hip/hip_runtime.h>
#include <hip/hip_bf16.h>

typedef _Float16 f16x8 __attribute__((ext_vector_type(8)));
typedef _Float16 f16x4 __attribute__((ext_vector_type(4)));
typedef float f32x4 __attribute__((ext_vector_type(4)));

#define B_   16
#define NL   256
#define NP   2048
#define NH   8
#define PSPLIT 8
#define PCHUNK (NP / PSPLIT)   // 256

static __device__ __forceinline__ f32x4 mfma16(f16x8 a, f16x8 b, f32x4 c) {
  return __builtin_amdgcn_mfma_f32_16x16x32_f16(a, b, c, 0, 0, 0);
}

// ---------------- projection: x[b][n][64] @ W[64][512] + bias, relu ----------------
__global__ __launch_bounds__(256) void proj_kernel(
    const float* __restrict__ x, const float* __restrict__ W, const float* __restrict__ bias,
    _Float16* __restrict__ outA, _Float16* __restrict__ outB, int N, int mode)
{
  __shared__ float xt[64][68];
  const int t = threadIdx.x;
  const int n0 = blockIdx.x * 64;
  const int h  = blockIdx.y;
  const int b  = blockIdx.z;

  const float* xp = x + ((size_t)b * N + n0) * 64;
#pragma unroll
  for (int i = 0; i < 4; ++i) {
    int flat = (i * 256 + t) * 4;
    f32x4 v = *(const f32x4*)(xp + flat);
    *(f32x4*)&xt[flat >> 6][flat & 63] = v;
  }
  __syncthreads();

  const int nb = (t >> 4) * 4;
  const int db = (t & 15) * 4;

  float acc[4][4];
#pragma unroll
  for (int i = 0; i < 4; ++i)
#pragma unroll
    for (int j = 0; j < 4; ++j) acc[i][j] = bias[h * 64 + db + j];

  const float* wp = W + h * 64 + db;
#pragma unroll 8
  for (int k = 0; k < 64; ++k) {
    f32x4 wq = *(const f32x4*)(wp + (size_t)k * 512);
    float a0 = xt[nb + 0][k], a1 = xt[nb + 1][k], a2 = xt[nb + 2][k], a3 = xt[nb + 3][k];
#pragma unroll
    for (int j = 0; j < 4; ++j) {
      acc[0][j] += a0 * wq[j];
      acc[1][j] += a1 * wq[j];
      acc[2][j] += a2 * wq[j];
      acc[3][j] += a3 * wq[j];
    }
  }

  if (mode == 0) {
#pragma unroll
    for (int i = 0; i < 4; ++i) {
      f16x4 hv, lv;
#pragma unroll
      for (int j = 0; j < 4; ++j) {
        float v = fmaxf(acc[i][j], 0.f);
        _Float16 hi = (_Float16)v;
        hv[j] = hi;
        lv[j] = (_Float16)((v - (float)hi) * 2048.0f);
      }
      size_t idx = (((size_t)b * NH + h) * N + n0 + nb + i) * 64 + db;
      *(f16x4*)(outA + idx) = hv;
      *(f16x4*)(outB + idx) = lv;
    }
  } else {
#pragma unroll
    for (int j = 0; j < 4; ++j) {
      f16x4 tv;
#pragma unroll
      for (int i = 0; i < 4; ++i) tv[i] = (_Float16)fmaxf(acc[i][j], 0.f);
      size_t idx = (((size_t)b * NH + h) * 64 + db + j) * N + n0 + nb;
      *(f16x4*)(outA + idx) = tv;
    }
  }
}

// ---------------- flash pass: 4 heads/block, db-dist, 1 barrier/iter ----------------
// grid: x = sp + PSPLIT*b (128), y = lt (16), z = hg (2)
// all (y,z) blocks of one x share the p1/p2 chunk + dist chunk -> same XCD
__global__ __launch_bounds__(256) void flash_l3_kernel(
    const _Float16* __restrict__ l1h, const _Float16* __restrict__ l1l,
    const _Float16* __restrict__ p1h, const _Float16* __restrict__ p1l,
    const _Float16* __restrict__ p2t, const float* __restrict__ dist,
    float* __restrict__ l3p, float* __restrict__ mpart, float* __restrict__ spart)
{
  const int sb = blockIdx.x;
  const int sp = sb & (PSPLIT - 1);
  const int b  = sb >> 3;
  const int lt = blockIdx.y;
  const int hg = blockIdx.z;
  const int t  = threadIdx.x;
  const int w    = t >> 6;            // wave 0..3
  const int h    = hg * 4 + w;
  const int lane = t & 63;
  const int g = lane >> 4, c = lane & 15;
  const int l0 = lt * 16;
  const int bh = b * NH + h;
  const int NT = PCHUNK / 64;         // 4

  __shared__ float distT[2][64][17];  // [buf][p-local][l-local], stride 17 = conflict-free writes
  __shared__ _Float16 P[4][16][72];   // per-wave scratch

  const size_t l1off = ((size_t)bh * NL + l0 + c) * 64;
  f16x8 aLh[2], aLl[2];
  aLh[0] = *(const f16x8*)(l1h + l1off + g * 8);
  aLh[1] = *(const f16x8*)(l1h + l1off + 32 + g * 8);
  aLl[0] = *(const f16x8*)(l1l + l1off + g * 8);
  aLl[1] = *(const f16x8*)(l1l + l1off + 32 + g * 8);

  f32x4 accO[4];
#pragma unroll
  for (int dt = 0; dt < 4; ++dt) accO[dt] = (f32x4){0.f, 0.f, 0.f, 0.f};
  float m_r[4] = {-INFINITY, -INFINITY, -INFINITY, -INFINITY};
  float s_r[4] = {0.f, 0.f, 0.f, 0.f};

  const float* dbase = dist + ((size_t)b * NL + l0) * NP + sp * PCHUNK;
  const _Float16* p1hb = p1h + ((size_t)bh * NP + sp * PCHUNK) * 64;
  const _Float16* p1lb = p1l + ((size_t)bh * NP + sp * PCHUNK) * 64;
  const _Float16* p2tb = p2t + (size_t)bh * 64 * NP + sp * PCHUNK;
  const float fh = (float)h, fh3 = fh + 3.0f;

  const int dl_p = t & 63;            // coop stage: p-local; wave w stages l rows 4w..4w+3

  // prologue: stage dist tile 0
#pragma unroll
  for (int i = 0; i < 4; ++i)
    distT[0][dl_p][w * 4 + i] = dbase[(size_t)(w * 4 + i) * NP + dl_p];

#pragma unroll 1
  for (int it = 0; it < NT; ++it) {
    const int P0 = it * 64;
    const int cur = it & 1;
    __syncthreads();                  // distT[cur] ready; [cur^1] free

    // prefetch next dist tile into 4 scalar regs (lands during full tile of compute)
    float nv[4];
    if (it + 1 < NT) {
#pragma unroll
      for (int i = 0; i < 4; ++i)
        nv[i] = dbase[(size_t)(w * 4 + i) * NP + P0 + 64 + dl_p];
    }

    float mev[4][4];
    float cmax[4] = {-INFINITY, -INFINITY, -INFINITY, -INFINITY};
#pragma unroll
    for (int s = 0; s < 4; ++s) {
      const _Float16* ph = p1hb + (size_t)(P0 + s * 16 + c) * 64;
      const _Float16* pl = p1lb + (size_t)(P0 + s * 16 + c) * 64;
      f16x8 bh0 = *(const f16x8*)(ph + g * 8);
      f16x8 bh1 = *(const f16x8*)(ph + 32 + g * 8);
      f16x8 bl0 = *(const f16x8*)(pl + g * 8);
      f16x8 bl1 = *(const f16x8*)(pl + 32 + g * 8);
      f32x4 e  = (f32x4){0.f, 0.f, 0.f, 0.f};
      f32x4 ec = (f32x4){0.f, 0.f, 0.f, 0.f};
      __builtin_amdgcn_s_setprio(1);
      e  = mfma16(aLh[0], bh0, e);  e  = mfma16(aLh[1], bh1, e);
      ec = mfma16(aLh[0], bl0, ec); ec = mfma16(aLh[1], bl1, ec);
      ec = mfma16(aLl[0], bh0, ec); ec = mfma16(aLl[1], bh1, ec);
      __builtin_amdgcn_s_setprio(0);
#pragma unroll
      for (int r = 0; r < 4; ++r) {
        float dv = distT[cur][s * 16 + c][g * 4 + r];
        float ev = (e[r] + ec[r] * (1.0f / 2048.0f)) * 0.125f;
        bool cond = (h < 7) ? (dv > fh && dv <= fh3) : (dv > 7.0f);
        float m = cond ? ev * __builtin_amdgcn_rcpf(dv) : 0.0f;
        mev[s][r] = m;
        cmax[r] = fmaxf(cmax[r], m);
      }
    }
#pragma unroll
    for (int mask = 1; mask < 16; mask <<= 1)
#pragma unroll
      for (int r = 0; r < 4; ++r)
        cmax[r] = fmaxf(cmax[r], __shfl_xor(cmax[r], mask, 64));

#pragma unroll
    for (int r = 0; r < 4; ++r) {
      float mn  = fmaxf(m_r[r], cmax[r]);
      float fac = __expf(m_r[r] - mn);
      m_r[r] = mn;
      float ss = 0.f;
#pragma unroll
      for (int s = 0; s < 4; ++s) {
        float pv = __expf(mev[s][r] - mn);
        ss += pv;
        P[w][g * 4 + r][s * 16 + c] = (_Float16)pv;
      }
      s_r[r] = s_r[r] * fac + ss;
#pragma unroll
      for (int dt = 0; dt < 4; ++dt) accO[dt][r] *= fac;
    }
    // PV (per-wave LDS dep; compiler inserts lgkmcnt)
#pragma unroll
    for (int kk = 0; kk < 2; ++kk) {
      f16x8 aP = *(const f16x8*)&P[w][c][kk * 32 + g * 8];
      __builtin_amdgcn_s_setprio(1);
#pragma unroll
      for (int dt = 0; dt < 4; ++dt) {
        f16x8 bV = *(const f16x8*)(p2tb + (size_t)(dt * 16 + c) * NP + P0 + kk * 32 + g * 8);
        accO[dt] = mfma16(aP, bV, accO[dt]);
      }
      __builtin_amdgcn_s_setprio(0);
    }
    // stage next dist tile into alternate buffer
    if (it + 1 < NT) {
#pragma unroll
      for (int i = 0; i < 4; ++i)
        distT[cur ^ 1][dl_p][w * 4 + i] = nv[i];
    }
  }

#pragma unroll
  for (int mask = 1; mask < 16; mask <<= 1)
#pragma unroll
    for (int r = 0; r < 4; ++r) s_r[r] += __shfl_xor(s_r[r], mask, 64);

  float* lp = l3p + (size_t)sp * B_ * NL * 512;
#pragma unroll
  for (int dt = 0; dt < 4; ++dt)
#pragma unroll
    for (int r = 0; r < 4; ++r)
      lp[((size_t)b * NL + l0 + g * 4 + r) * 512 + h * 64 + dt * 16 + c] = accO[dt][r];

  if (c == 0) {
#pragma unroll
    for (int r = 0; r < 4; ++r) {
      size_t li = (size_t)sp * B_ * NH * NL + (size_t)bh * NL + l0 + g * 4 + r;
      mpart[li] = m_r[r];
      spart[li] = s_r[r];
    }
  }
}

// ---------------- merge split-P partials ----------------
__global__ __launch_bounds__(256) void merge_l3_kernel(
    const float* __restrict__ l3p, const float* __restrict__ mpart, const float* __restrict__ spart,
    float* __restrict__ l3c, float* __restrict__ mrow, float* __restrict__ rsrow)
{
  const int row = blockIdx.x * 4 + (threadIdx.x >> 6);
  const int d   = threadIdx.x & 63;
  const int l   = row & (NL - 1);
  const int bh  = row >> 8;
  const int b = bh >> 3, h = bh & 7;
  const size_t srow = (size_t)B_ * NH * NL;

  float mi[PSPLIT], si[PSPLIT];
  float M = -INFINITY;
#pragma unroll
  for (int i = 0; i < PSPLIT; ++i) {
    mi[i] = mpart[(size_t)i * srow + row];
    si[i] = spart[(size_t)i * srow + row];
    M = fmaxf(M, mi[i]);
  }
  const float* lp = l3p + ((size_t)b * NL + l) * 512 + h * 64 + d;
  float S = 0.f, o = 0.f;
#pragma unroll
  for (int i = 0; i < PSPLIT; ++i) {
    float w = __expf(mi[i] - M);
    S += si[i] * w;
    o += lp[(size_t)i * B_ * NL * 512] * w;
  }
  float rs = 1.0f / S;
  l3c[((size_t)b * NL + l) * 512 + h * 64 + d] = o * rs;
  if (d == 0) { mrow[row] = M; rsrow[row] = rs; }
}

// ---------------- pass 2: p3 = att^T @ l2, 4 heads/block, db-dist, 1 barrier/iter ----------------
// grid: x = b (16), y = pt (128), z = hg (2) : all pt-blocks of a batch colocate per XCD
__global__ __launch_bounds__(256) void p3_kernel(
    const _Float16* __restrict__ p1h, const _Float16* __restrict__ p1l,
    const _Float16* __restrict__ l1h, const _Float16* __restrict__ l1l,
    const _Float16* __restrict__ l2t, const float* __restrict__ dist,
    const float* __restrict__ mrow, const float* __restrict__ rsrow,
    float* __restrict__ p3c)
{
  const int b  = blockIdx.x;
  const int pt = blockIdx.y;
  const int hg = blockIdx.z;
  const int t  = threadIdx.x;
  const int w    = t >> 6;
  const int h    = hg * 4 + w;
  const int lane = t & 63;
  const int g = lane >> 4, c = lane & 15;
  const int p0 = pt * 16;
  const int bh = b * NH + h;
  const int NT = NL / 32;             // 8

  __shared__ float distT[2][32][20];  // [buf][l-local][p-local]
  __shared__ _Float16 PT[4][16][40];  // per-wave

  const size_t poff = ((size_t)bh * NP + p0 + c) * 64;
  f16x8 aPh[2], aPl[2];
  aPh[0] = *(const f16x8*)(p1h + poff + g * 8);
  aPh[1] = *(const f16x8*)(p1h + poff + 32 + g * 8);
  aPl[0] = *(const f16x8*)(p1l + poff + g * 8);
  aPl[1] = *(const f16x8*)(p1l + poff + 32 + g * 8);

  f32x4 acc[4];
#pragma unroll
  for (int dt = 0; dt < 4; ++dt) acc[dt] = (f32x4){0.f, 0.f, 0.f, 0.f};

  const float* db_ = dist + (size_t)b * NL * NP + p0;
  const _Float16* l1hb = l1h + (size_t)bh * NL * 64;
  const _Float16* l1lb = l1l + (size_t)bh * NL * 64;
  const _Float16* l2tb = l2t + (size_t)bh * 64 * NL;
  const float* mb = mrow + (size_t)bh * NL;
  const float* rb = rsrow + (size_t)bh * NL;
  const float fh = (float)h, fh3 = fh + 3.0f;

  const int dl_l = t >> 4;            // 0..15 ; rows dl_l, dl_l+16
  const int dl_p = t & 15;

  // prologue: stage dist tile 0
#pragma unroll
  for (int i = 0; i < 2; ++i)
    distT[0][dl_l + 16 * i][dl_p] = db_[(size_t)(dl_l + 16 * i) * NP + dl_p];

#pragma unroll 1
  for (int it = 0; it < NT; ++it) {
    const int lc = it * 32;
    const int cur = it & 1;
    __syncthreads();

    float nv[2];
    if (it + 1 < NT) {
#pragma unroll
      for (int i = 0; i < 2; ++i)
        nv[i] = db_[(size_t)(lc + 32 + dl_l + 16 * i) * NP + dl_p];
    }

#pragma unroll
    for (int s = 0; s < 2; ++s) {
      const int l = lc + s * 16 + c;
      const _Float16* lhp = l1hb + (size_t)l * 64;
      const _Float16* llp = l1lb + (size_t)l * 64;
      f16x8 bh0 = *(const f16x8*)(lhp + g * 8);
      f16x8 bh1 = *(const f16x8*)(lhp + 32 + g * 8);
      f16x8 bl0 = *(const f16x8*)(llp + g * 8);
      f16x8 bl1 = *(const f16x8*)(llp + 32 + g * 8);
      f32x4 e  = (f32x4){0.f, 0.f, 0.f, 0.f};
      f32x4 ec = (f32x4){0.f, 0.f, 0.f, 0.f};
      __builtin_amdgcn_s_setprio(1);
      e  = mfma16(aPh[0], bh0, e);  e  = mfma16(aPh[1], bh1, e);
      ec = mfma16(aPh[0], bl0, ec); ec = mfma16(aPh[1], bl1, ec);
      ec = mfma16(aPl[0], bh0, ec); ec = mfma16(aPl[1], bh1, ec);
      __builtin_amdgcn_s_setprio(0);
      float ml = mb[l], rl = rb[l];
      f32x4 dq = *(const f32x4*)&distT[cur][s * 16 + c][g * 4];
#pragma unroll
      for (int r = 0; r < 4; ++r) {
        float ev = (e[r] + ec[r] * (1.0f / 2048.0f)) * 0.125f;
        float dvv = dq[r];
        bool cond = (h < 7) ? (dvv > fh && dvv <= fh3) : (dvv > 7.0f);
        float m = cond ? ev * __builtin_amdgcn_rcpf(dvv) : 0.0f;
        float att = __expf(m - ml) * rl;
        PT[w][g * 4 + r][s * 16 + c] = (_Float16)att;
      }
    }
    {
      f16x8 aA = *(const f16x8*)&PT[w][c][g * 8];
      __builtin_amdgcn_s_setprio(1);
#pragma unroll
      for (int dt = 0; dt < 4; ++dt) {
        f16x8 bV = *(const f16x8*)(l2tb + (size_t)(dt * 16 + c) * NL + lc + g * 8);
        acc[dt] = mfma16(aA, bV, acc[dt]);
      }
      __builtin_amdgcn_s_setprio(0);
    }
    if (it + 1 < NT) {
#pragma unroll
      for (int i = 0; i < 2; ++i)
        distT[cur ^ 1][dl_l + 16 * i][dl_p] = nv[i];
    }
  }

#pragma unroll
  for (int dt = 0; dt < 4; ++dt)
#pragma unroll
    for (int r = 0; r < 4; ++r)
      p3c[((size_t)b * NP + p0 + g * 4 + r) * 512 + h * 64 + dt * 16 + c] = acc[dt][r];
}

// ---------------- FC chain ----------------
__global__ __launch_bounds__(256) void fc_out_kernel(
    const float* __restrict__ x3c, const float* __restrict__ xbase,
    const float* __restrict__ wA, const float* __restrict__ bA,
    const float* __restrict__ wB, const float* __restrict__ bB,
    float* __restrict__ out, int N, int out_off)
{
  __shared__ float xl[16][520];
  __shared__ float t1[16][68];
  __shared__ float xb[16][68];
  const int t = threadIdx.x;
  const int row0 = blockIdx.x * 16;

  const float* xp = x3c + (size_t)row0 * 512;
#pragma unroll
  for (int i = 0; i < 8; ++i) {
    int flat = (i * 256 + t) * 4;
    f32x4 v = *(const f32x4*)(xp + flat);
    *(f32x4*)&xl[flat >> 9][flat & 511] = v;
  }
  {
    const float* bp = xbase + (size_t)row0 * 64;
    int flat = t * 4;
    f32x4 v = *(const f32x4*)(bp + flat);
    *(f32x4*)&xb[flat >> 6][flat & 63] = v;
  }
  __syncthreads();

  const int r  = t >> 4;
  const int c4 = (t & 15) * 4;

  float acc[4];
#pragma unroll
  for (int j = 0; j < 4; ++j) acc[j] = bA[c4 + j];
  for (int k4 = 0; k4 < 128; ++k4) {
    f32x4 xq = *(const f32x4*)&xl[r][k4 * 4];
#pragma unroll
    for (int kk = 0; kk < 4; ++kk) {
      f32x4 wq = *(const f32x4*)(wA + (size_t)(k4 * 4 + kk) * 64 + c4);
#pragma unroll
      for (int j = 0; j < 4; ++j) acc[j] += xq[kk] * wq[j];
    }
  }
#pragma unroll
  for (int j = 0; j < 4; ++j) t1[r][c4 + j] = acc[j];
  __syncthreads();

  float a2[4];
#pragma unroll
  for (int j = 0; j < 4; ++j) a2[j] = bB[c4 + j];
  for (int k4 = 0; k4 < 32; ++k4) {
    f32x4 xq = (k4 < 16) ? *(const f32x4*)&t1[r][k4 * 4]
                         : *(const f32x4*)&xb[r][k4 * 4 - 64];
#pragma unroll
    for (int kk = 0; kk < 4; ++kk) {
      f32x4 wq = *(const f32x4*)(wB + (size_t)(k4 * 4 + kk) * 64 + c4);
#pragma unroll
      for (int j = 0; j < 4; ++j) a2[j] += xq[kk] * wq[j];
    }
  }
  const int row = row0 + r;
  const int b = row / N, n = row % N;
  f32x4 o;
#pragma unroll
  for (int j = 0; j < 4; ++j) o[j] = fmaxf(a2[j], 0.f);
  *(f32x4*)(out + (((size_t)b * (NL + NP)) + out_off + n) * 64 + c4) = o;
}

extern "C" void kernel_launch(void* const* d_in, const int* in_sizes, int n_in,
                              void* d_out, int out_size, void* d_ws, size_t ws_size,
                              hipStream_t stream)
{
  const float* ligand = (const float*)d_in[0];
  const float* prot   = (const float*)d_in[1];
  const float* dist   = (const float*)d_in[2];
  const float* w_l1   = (const float*)d_in[3];
  const float* b_l1   = (const float*)d_in[4];
  const float* w_l2   = (const float*)d_in[5];
  const float* b_l2   = (const float*)d_in[6];
  const float* w_p1   = (const float*)d_in[7];
  const float* b_p1   = (const float*)d_in[8];
  const float* w_p2   = (const float*)d_in[9];
  const float* b_p2   = (const float*)d_in[10];
  const float* fc11_w = (const float*)d_in[11];
  const float* fc11_b = (const float*)d_in[12];
  const float* fc12_w = (const float*)d_in[13];
  const float* fc12_b = (const float*)d_in[14];
  const float* fc21_w = (const float*)d_in[15];
  const float* fc21_b = (const float*)d_in[16];
  const float* fc22_w = (const float*)d_in[17];
  const float* fc22_b = (const float*)d_in[18];
  float* out = (float*)d_out;

  char* ws = (char*)d_ws;
  size_t off = 0;
  auto alloc = [&](size_t bytes) -> void* {
    void* p = ws + off;
    off += (bytes + 255) & ~(size_t)255;
    return p;
  };
  const size_t L1E = (size_t)B_ * NH * NL * 64;
  const size_t P1E = (size_t)B_ * NH * NP * 64;
  _Float16* l1h = (_Float16*)alloc(L1E * 2);
  _Float16* l1l = (_Float16*)alloc(L1E * 2);
  _Float16* p1h = (_Float16*)alloc(P1E * 2);
  _Float16* p1l = (_Float16*)alloc(P1E * 2);
  _Float16* l2t = (_Float16*)alloc(L1E * 2);
  _Float16* p2t = (_Float16*)alloc(P1E * 2);
  float* mrow  = (float*)alloc((size_t)B_ * NH * NL * 4);
  float* rsrow = (float*)alloc((size_t)B_ * NH * NL * 4);
  float* mpart = (float*)alloc((size_t)PSPLIT * B_ * NH * NL * 4);
  float* spart = (float*)alloc((size_t)PSPLIT * B_ * NH * NL * 4);
  float* l3c = (float*)alloc((size_t)B_ * NL * 512 * 4);
  float* p3c = (float*)alloc((size_t)B_ * NP * 512 * 4);
  float* l3p = p3c;   // alias: l3 partials (PSPLIT*B*NL*512*4 = 67 MB) dead before p3 writes p3c (67 MB)

  proj_kernel<<<dim3(NL / 64, NH, B_), 256, 0, stream>>>(ligand, w_l1, b_l1, l1h, l1l, NL, 0);
  proj_kernel<<<dim3(NL / 64, NH, B_), 256, 0, stream>>>(ligand, w_l2, b_l2, l2t, nullptr, NL, 1);
  proj_kernel<<<dim3(NP / 64, NH, B_), 256, 0, stream>>>(prot, w_p1, b_p1, p1h, p1l, NP, 0);
  proj_kernel<<<dim3(NP / 64, NH, B_), 256, 0, stream>>>(prot, w_p2, b_p2, p2t, nullptr, NP, 1);

  flash_l3_kernel<<<dim3(PSPLIT * B_, NL / 16, 2), 256, 0, stream>>>(
      l1h, l1l, p1h, p1l, p2t, dist, l3p, mpart, spart);
  merge_l3_kernel<<<(B_ * NH * NL) / 4, 256, 0, stream>>>(l3p, mpart, spart, l3c, mrow, rsrow);
  p3_kernel<<<dim3(B_, NP / 16, 2), 256, 0, stream>>>(p1h, p1l, l1h, l1l, l2t, dist,
                                                      mrow, rsrow, p3c);

  fc_out_kernel<<<(B_ * NL) / 16, 256, 0, stream>>>(l3c, ligand, fc11_w, fc11_b,
                                                    fc12_w, fc12_b, out, NL, 0);
  fc_out_kernel<<<(B_ * NP) / 16, 256, 0, stream>>>(p3c, prot, fc21_w, fc21_b,
                                                    fc22_w, fc22_b, out, NP, NL);
}

// Round 6
// 794.707 us; speedup vs baseline: 1.0954x; 1.0056x over previous
//
#include <hip/hip_runtime.h>
#include <hip/hip_bf16.h>

typedef _Float16 f16x8 __attribute__((ext_vector_type(8)));
typedef _Float16 f16x4 __attribute__((ext_vector_type(4)));
typedef float f32x4 __attribute__((ext_vector_type(4)));

#define B_   16
#define NL   256
#define NP   2048
#define NH   8
#define PSPLIT 4
#define PCHUNK (NP / PSPLIT)   // 512

static __device__ __forceinline__ f32x4 mfma16(f16x8 a, f16x8 b, f32x4 c) {
  return __builtin_amdgcn_mfma_f32_16x16x32_f16(a, b, c, 0, 0, 0);
}

// ---------------- projection: x[b][n][64] @ W[64][512] + bias, relu ----------------
__global__ __launch_bounds__(256) void proj_kernel(
    const float* __restrict__ x, const float* __restrict__ W, const float* __restrict__ bias,
    _Float16* __restrict__ outA, _Float16* __restrict__ outB, int N, int mode)
{
  __shared__ float xt[64][68];
  const int t = threadIdx.x;
  const int n0 = blockIdx.x * 64;
  const int h  = blockIdx.y;
  const int b  = blockIdx.z;

  const float* xp = x + ((size_t)b * N + n0) * 64;
#pragma unroll
  for (int i = 0; i < 4; ++i) {
    int flat = (i * 256 + t) * 4;
    f32x4 v = *(const f32x4*)(xp + flat);
    *(f32x4*)&xt[flat >> 6][flat & 63] = v;
  }
  __syncthreads();

  const int nb = (t >> 4) * 4;
  const int db = (t & 15) * 4;

  float acc[4][4];
#pragma unroll
  for (int i = 0; i < 4; ++i)
#pragma unroll
    for (int j = 0; j < 4; ++j) acc[i][j] = bias[h * 64 + db + j];

  const float* wp = W + h * 64 + db;
#pragma unroll 8
  for (int k = 0; k < 64; ++k) {
    f32x4 wq = *(const f32x4*)(wp + (size_t)k * 512);
    float a0 = xt[nb + 0][k], a1 = xt[nb + 1][k], a2 = xt[nb + 2][k], a3 = xt[nb + 3][k];
#pragma unroll
    for (int j = 0; j < 4; ++j) {
      acc[0][j] += a0 * wq[j];
      acc[1][j] += a1 * wq[j];
      acc[2][j] += a2 * wq[j];
      acc[3][j] += a3 * wq[j];
    }
  }

  if (mode == 0) {
#pragma unroll
    for (int i = 0; i < 4; ++i) {
      f16x4 hv, lv;
#pragma unroll
      for (int j = 0; j < 4; ++j) {
        float v = fmaxf(acc[i][j], 0.f);
        _Float16 hi = (_Float16)v;
        hv[j] = hi;
        lv[j] = (_Float16)((v - (float)hi) * 2048.0f);
      }
      size_t idx = (((size_t)b * NH + h) * N + n0 + nb + i) * 64 + db;
      *(f16x4*)(outA + idx) = hv;
      *(f16x4*)(outB + idx) = lv;
    }
  } else {
#pragma unroll
    for (int j = 0; j < 4; ++j) {
      f16x4 tv;
#pragma unroll
      for (int i = 0; i < 4; ++i) tv[i] = (_Float16)fmaxf(acc[i][j], 0.f);
      size_t idx = (((size_t)b * NH + h) * 64 + db + j) * N + n0 + nb;
      *(f16x4*)(outA + idx) = tv;
    }
  }
}

// ---------------- flash pass: 4 heads/block, staged d + 0.125/d, 1 barrier/iter ----------------
// grid: x = sp + PSPLIT*b (64), y = lt (16), z = hg (2)
// blocks sharing one x (same p1/p2/dist chunk) land on one XCD (y,z strides are %8==0)
__global__ __launch_bounds__(256) void flash_l3_kernel(
    const _Float16* __restrict__ l1h, const _Float16* __restrict__ l1l,
    const _Float16* __restrict__ p1h, const _Float16* __restrict__ p1l,
    const _Float16* __restrict__ p2t, const float* __restrict__ dist,
    float* __restrict__ l3p, float* __restrict__ mpart, float* __restrict__ spart)
{
  const int sb = blockIdx.x;
  const int sp = sb & (PSPLIT - 1);
  const int b  = sb >> 2;
  const int lt = blockIdx.y;
  const int hg = blockIdx.z;
  const int t  = threadIdx.x;
  const int w    = t >> 6;            // wave 0..3
  const int h    = hg * 4 + w;
  const int lane = t & 63;
  const int g = lane >> 4, c = lane & 15;
  const int l0 = lt * 16;
  const int bh = b * NH + h;
  const int NT = PCHUNK / 64;         // 8

  __shared__ float dT[2][64][20];     // [buf][p-local][l-local] raw d  (b128-readable)
  __shared__ float rT[2][64][20];     // [buf][p-local][l-local] 0.125/d
  __shared__ _Float16 P[4][16][72];   // per-wave scratch

  const size_t l1off = ((size_t)bh * NL + l0 + c) * 64;
  f16x8 aLh[2], aLl[2];
  aLh[0] = *(const f16x8*)(l1h + l1off + g * 8);
  aLh[1] = *(const f16x8*)(l1h + l1off + 32 + g * 8);
  aLl[0] = *(const f16x8*)(l1l + l1off + g * 8);
  aLl[1] = *(const f16x8*)(l1l + l1off + 32 + g * 8);

  f32x4 accO[4];
#pragma unroll
  for (int dt = 0; dt < 4; ++dt) accO[dt] = (f32x4){0.f, 0.f, 0.f, 0.f};
  float m_r[4] = {-INFINITY, -INFINITY, -INFINITY, -INFINITY};
  float s_r[4] = {0.f, 0.f, 0.f, 0.f};

  const float* dbase = dist + ((size_t)b * NL + l0) * NP + sp * PCHUNK;
  const _Float16* p1hb = p1h + ((size_t)bh * NP + sp * PCHUNK) * 64;
  const _Float16* p1lb = p1l + ((size_t)bh * NP + sp * PCHUNK) * 64;
  const _Float16* p2tb = p2t + (size_t)bh * 64 * NP + sp * PCHUNK;
  const float fh = (float)h, fh3 = fh + 3.0f;

  const int dl_p = t & 63;            // coop stage: p-local; wave w stages l rows 4w..4w+3

  // prologue: stage dist tile 0 (d and 0.125/d)
#pragma unroll
  for (int i = 0; i < 4; ++i) {
    float dv = dbase[(size_t)(w * 4 + i) * NP + dl_p];
    dT[0][dl_p][w * 4 + i] = dv;
    rT[0][dl_p][w * 4 + i] = 0.125f * __builtin_amdgcn_rcpf(dv);
  }

#pragma unroll 1
  for (int it = 0; it < NT; ++it) {
    const int P0 = it * 64;
    const int cur = it & 1;
    __syncthreads();                  // tiles[cur] ready; [cur^1] free

    // prefetch next dist tile into 4 scalar regs
    float nv[4];
    if (it + 1 < NT) {
#pragma unroll
      for (int i = 0; i < 4; ++i)
        nv[i] = dbase[(size_t)(w * 4 + i) * NP + P0 + 64 + dl_p];
    }

    float mev[4][4];
    float cmax[4] = {-INFINITY, -INFINITY, -INFINITY, -INFINITY};
#pragma unroll
    for (int s = 0; s < 4; ++s) {
      const _Float16* ph = p1hb + (size_t)(P0 + s * 16 + c) * 64;
      const _Float16* pl = p1lb + (size_t)(P0 + s * 16 + c) * 64;
      f16x8 bh0 = *(const f16x8*)(ph + g * 8);
      f16x8 bh1 = *(const f16x8*)(ph + 32 + g * 8);
      f16x8 bl0 = *(const f16x8*)(pl + g * 8);
      f16x8 bl1 = *(const f16x8*)(pl + 32 + g * 8);
      f32x4 e  = (f32x4){0.f, 0.f, 0.f, 0.f};
      f32x4 ec = (f32x4){0.f, 0.f, 0.f, 0.f};
      __builtin_amdgcn_s_setprio(1);
      e  = mfma16(aLh[0], bh0, e);  e  = mfma16(aLh[1], bh1, e);
      ec = mfma16(aLh[0], bl0, ec); ec = mfma16(aLh[1], bl1, ec);
      ec = mfma16(aLl[0], bh0, ec); ec = mfma16(aLl[1], bh1, ec);
      __builtin_amdgcn_s_setprio(0);
      f32x4 dq = *(const f32x4*)&dT[cur][s * 16 + c][g * 4];
      f32x4 rq = *(const f32x4*)&rT[cur][s * 16 + c][g * 4];
#pragma unroll
      for (int r = 0; r < 4; ++r) {
        float dv = dq[r];
        bool cond = (h < 7) ? (dv > fh && dv <= fh3) : (dv > 7.0f);
        float rm = cond ? rq[r] : 0.0f;
        float evv = fmaf(ec[r], 1.0f / 2048.0f, e[r]);
        float m = evv * rm;
        mev[s][r] = m;
        cmax[r] = fmaxf(cmax[r], m);
      }
    }
#pragma unroll
    for (int mask = 1; mask < 16; mask <<= 1)
#pragma unroll
      for (int r = 0; r < 4; ++r)
        cmax[r] = fmaxf(cmax[r], __shfl_xor(cmax[r], mask, 64));

#pragma unroll
    for (int r = 0; r < 4; ++r) {
      float mn  = fmaxf(m_r[r], cmax[r]);
      float fac = __expf(m_r[r] - mn);
      m_r[r] = mn;
      float ss = 0.f;
#pragma unroll
      for (int s = 0; s < 4; ++s) {
        float pv = __expf(mev[s][r] - mn);
        ss += pv;
        P[w][g * 4 + r][s * 16 + c] = (_Float16)pv;
      }
      s_r[r] = s_r[r] * fac + ss;
#pragma unroll
      for (int dt = 0; dt < 4; ++dt) accO[dt][r] *= fac;
    }
    // PV (per-wave LDS dep; compiler inserts lgkmcnt)
#pragma unroll
    for (int kk = 0; kk < 2; ++kk) {
      f16x8 aP = *(const f16x8*)&P[w][c][kk * 32 + g * 8];
      __builtin_amdgcn_s_setprio(1);
#pragma unroll
      for (int dt = 0; dt < 4; ++dt) {
        f16x8 bV = *(const f16x8*)(p2tb + (size_t)(dt * 16 + c) * NP + P0 + kk * 32 + g * 8);
        accO[dt] = mfma16(aP, bV, accO[dt]);
      }
      __builtin_amdgcn_s_setprio(0);
    }
    // stage next dist tile (d + 0.125/d) into alternate buffer
    if (it + 1 < NT) {
#pragma unroll
      for (int i = 0; i < 4; ++i) {
        dT[cur ^ 1][dl_p][w * 4 + i] = nv[i];
        rT[cur ^ 1][dl_p][w * 4 + i] = 0.125f * __builtin_amdgcn_rcpf(nv[i]);
      }
    }
  }

#pragma unroll
  for (int mask = 1; mask < 16; mask <<= 1)
#pragma unroll
    for (int r = 0; r < 4; ++r) s_r[r] += __shfl_xor(s_r[r], mask, 64);

  float* lp = l3p + (size_t)sp * B_ * NL * 512;
#pragma unroll
  for (int dt = 0; dt < 4; ++dt)
#pragma unroll
    for (int r = 0; r < 4; ++r)
      lp[((size_t)b * NL + l0 + g * 4 + r) * 512 + h * 64 + dt * 16 + c] = accO[dt][r];

  if (c == 0) {
#pragma unroll
    for (int r = 0; r < 4; ++r) {
      size_t li = (size_t)sp * B_ * NH * NL + (size_t)bh * NL + l0 + g * 4 + r;
      mpart[li] = m_r[r];
      spart[li] = s_r[r];
    }
  }
}

// ---------------- merge split-P partials; mrow <- LSE = M + ln(S) ----------------
__global__ __launch_bounds__(256) void merge_l3_kernel(
    const float* __restrict__ l3p, const float* __restrict__ mpart, const float* __restrict__ spart,
    float* __restrict__ l3c, float* __restrict__ mrow)
{
  const int row = blockIdx.x * 4 + (threadIdx.x >> 6);
  const int d   = threadIdx.x & 63;
  const int l   = row & (NL - 1);
  const int bh  = row >> 8;
  const int b = bh >> 3, h = bh & 7;
  const size_t srow = (size_t)B_ * NH * NL;

  float mi[PSPLIT], si[PSPLIT];
  float M = -INFINITY;
#pragma unroll
  for (int i = 0; i < PSPLIT; ++i) {
    mi[i] = mpart[(size_t)i * srow + row];
    si[i] = spart[(size_t)i * srow + row];
    M = fmaxf(M, mi[i]);
  }
  const float* lp = l3p + ((size_t)b * NL + l) * 512 + h * 64 + d;
  float S = 0.f, o = 0.f;
#pragma unroll
  for (int i = 0; i < PSPLIT; ++i) {
    float w = __expf(mi[i] - M);
    S += si[i] * w;
    o += lp[(size_t)i * B_ * NL * 512] * w;
  }
  l3c[((size_t)b * NL + l) * 512 + h * 64 + d] = o / S;
  if (d == 0) mrow[row] = M + __logf(S);   // logsumexp
}

// ---------------- pass 2: p3 = att^T @ l2 ; att = exp(m - LSE) ----------------
// grid: x = b (16), y = pt (128), z = hg (2) : same-b blocks colocate per XCD
__global__ __launch_bounds__(256) void p3_kernel(
    const _Float16* __restrict__ p1h, const _Float16* __restrict__ p1l,
    const _Float16* __restrict__ l1h, const _Float16* __restrict__ l1l,
    const _Float16* __restrict__ l2t, const float* __restrict__ dist,
    const float* __restrict__ mrow,
    float* __restrict__ p3c)
{
  const int b  = blockIdx.x;
  const int pt = blockIdx.y;
  const int hg = blockIdx.z;
  const int t  = threadIdx.x;
  const int w    = t >> 6;
  const int h    = hg * 4 + w;
  const int lane = t & 63;
  const int g = lane >> 4, c = lane & 15;
  const int p0 = pt * 16;
  const int bh = b * NH + h;
  const int NT = NL / 32;             // 8

  __shared__ float dT[2][32][20];     // [buf][l-local][p-local] raw d
  __shared__ float rT[2][32][20];     // [buf][l-local][p-local] 0.125/d
  __shared__ _Float16 PT[4][16][40];  // per-wave

  const size_t poff = ((size_t)bh * NP + p0 + c) * 64;
  f16x8 aPh[2], aPl[2];
  aPh[0] = *(const f16x8*)(p1h + poff + g * 8);
  aPh[1] = *(const f16x8*)(p1h + poff + 32 + g * 8);
  aPl[0] = *(const f16x8*)(p1l + poff + g * 8);
  aPl[1] = *(const f16x8*)(p1l + poff + 32 + g * 8);

  f32x4 acc[4];
#pragma unroll
  for (int dt = 0; dt < 4; ++dt) acc[dt] = (f32x4){0.f, 0.f, 0.f, 0.f};

  const float* db_ = dist + (size_t)b * NL * NP + p0;
  const _Float16* l1hb = l1h + (size_t)bh * NL * 64;
  const _Float16* l1lb = l1l + (size_t)bh * NL * 64;
  const _Float16* l2tb = l2t + (size_t)bh * 64 * NL;
  const float* mb = mrow + (size_t)bh * NL;
  const float fh = (float)h, fh3 = fh + 3.0f;

  const int dl_l = t >> 4;            // 0..15 ; rows dl_l, dl_l+16
  const int dl_p = t & 15;

  // prologue: stage dist tile 0
#pragma unroll
  for (int i = 0; i < 2; ++i) {
    float dv = db_[(size_t)(dl_l + 16 * i) * NP + dl_p];
    dT[0][dl_l + 16 * i][dl_p] = dv;
    rT[0][dl_l + 16 * i][dl_p] = 0.125f * __builtin_amdgcn_rcpf(dv);
  }

#pragma unroll 1
  for (int it = 0; it < NT; ++it) {
    const int lc = it * 32;
    const int cur = it & 1;
    __syncthreads();

    float nv[2];
    if (it + 1 < NT) {
#pragma unroll
      for (int i = 0; i < 2; ++i)
        nv[i] = db_[(size_t)(lc + 32 + dl_l + 16 * i) * NP + dl_p];
    }

#pragma unroll
    for (int s = 0; s < 2; ++s) {
      const int l = lc + s * 16 + c;
      const _Float16* lhp = l1hb + (size_t)l * 64;
      const _Float16* llp = l1lb + (size_t)l * 64;
      f16x8 bh0 = *(const f16x8*)(lhp + g * 8);
      f16x8 bh1 = *(const f16x8*)(lhp + 32 + g * 8);
      f16x8 bl0 = *(const f16x8*)(llp + g * 8);
      f16x8 bl1 = *(const f16x8*)(llp + 32 + g * 8);
      f32x4 e  = (f32x4){0.f, 0.f, 0.f, 0.f};
      f32x4 ec = (f32x4){0.f, 0.f, 0.f, 0.f};
      __builtin_amdgcn_s_setprio(1);
      e  = mfma16(aPh[0], bh0, e);  e  = mfma16(aPh[1], bh1, e);
      ec = mfma16(aPh[0], bl0, ec); ec = mfma16(aPh[1], bl1, ec);
      ec = mfma16(aPl[0], bh0, ec); ec = mfma16(aPl[1], bh1, ec);
      __builtin_amdgcn_s_setprio(0);
      float lse = mb[l];
      f32x4 dq = *(const f32x4*)&dT[cur][s * 16 + c][g * 4];
      f32x4 rq = *(const f32x4*)&rT[cur][s * 16 + c][g * 4];
#pragma unroll
      for (int r = 0; r < 4; ++r) {
        float dvv = dq[r];
        bool cond = (h < 7) ? (dvv > fh && dvv <= fh3) : (dvv > 7.0f);
        float rm = cond ? rq[r] : 0.0f;
        float evv = fmaf(ec[r], 1.0f / 2048.0f, e[r]);
        float att = __expf(fmaf(evv, rm, -lse));
        PT[w][g * 4 + r][s * 16 + c] = (_Float16)att;
      }
    }
    {
      f16x8 aA = *(const f16x8*)&PT[w][c][g * 8];
      __builtin_amdgcn_s_setprio(1);
#pragma unroll
      for (int dt = 0; dt < 4; ++dt) {
        f16x8 bV = *(const f16x8*)(l2tb + (size_t)(dt * 16 + c) * NL + lc + g * 8);
        acc[dt] = mfma16(aA, bV, acc[dt]);
      }
      __builtin_amdgcn_s_setprio(0);
    }
    if (it + 1 < NT) {
#pragma unroll
      for (int i = 0; i < 2; ++i) {
        dT[cur ^ 1][dl_l + 16 * i][dl_p] = nv[i];
        rT[cur ^ 1][dl_l + 16 * i][dl_p] = 0.125f * __builtin_amdgcn_rcpf(nv[i]);
      }
    }
  }

#pragma unroll
  for (int dt = 0; dt < 4; ++dt)
#pragma unroll
    for (int r = 0; r < 4; ++r)
      p3c[((size_t)b * NP + p0 + g * 4 + r) * 512 + h * 64 + dt * 16 + c] = acc[dt][r];
}

// ---------------- FC chain ----------------
__global__ __launch_bounds__(256) void fc_out_kernel(
    const float* __restrict__ x3c, const float* __restrict__ xbase,
    const float* __restrict__ wA, const float* __restrict__ bA,
    const float* __restrict__ wB, const float* __restrict__ bB,
    float* __restrict__ out, int N, int out_off)
{
  __shared__ float xl[16][520];
  __shared__ float t1[16][68];
  __shared__ float xb[16][68];
  const int t = threadIdx.x;
  const int row0 = blockIdx.x * 16;

  const float* xp = x3c + (size_t)row0 * 512;
#pragma unroll
  for (int i = 0; i < 8; ++i) {
    int flat = (i * 256 + t) * 4;
    f32x4 v = *(const f32x4*)(xp + flat);
    *(f32x4*)&xl[flat >> 9][flat & 511] = v;
  }
  {
    const float* bp = xbase + (size_t)row0 * 64;
    int flat = t * 4;
    f32x4 v = *(const f32x4*)(bp + flat);
    *(f32x4*)&xb[flat >> 6][flat & 63] = v;
  }
  __syncthreads();

  const int r  = t >> 4;
  const int c4 = (t & 15) * 4;

  float acc[4];
#pragma unroll
  for (int j = 0; j < 4; ++j) acc[j] = bA[c4 + j];
  for (int k4 = 0; k4 < 128; ++k4) {
    f32x4 xq = *(const f32x4*)&xl[r][k4 * 4];
#pragma unroll
    for (int kk = 0; kk < 4; ++kk) {
      f32x4 wq = *(const f32x4*)(wA + (size_t)(k4 * 4 + kk) * 64 + c4);
#pragma unroll
      for (int j = 0; j < 4; ++j) acc[j] += xq[kk] * wq[j];
    }
  }
#pragma unroll
  for (int j = 0; j < 4; ++j) t1[r][c4 + j] = acc[j];
  __syncthreads();

  float a2[4];
#pragma unroll
  for (int j = 0; j < 4; ++j) a2[j] = bB[c4 + j];
  for (int k4 = 0; k4 < 32; ++k4) {
    f32x4 xq = (k4 < 16) ? *(const f32x4*)&t1[r][k4 * 4]
                         : *(const f32x4*)&xb[r][k4 * 4 - 64];
#pragma unroll
    for (int kk = 0; kk < 4; ++kk) {
      f32x4 wq = *(const f32x4*)(wB + (size_t)(k4 * 4 + kk) * 64 + c4);
#pragma unroll
      for (int j = 0; j < 4; ++j) a2[j] += xq[kk] * wq[j];
    }
  }
  const int row = row0 + r;
  const int b = row / N, n = row % N;
  f32x4 o;
#pragma unroll
  for (int j = 0; j < 4; ++j) o[j] = fmaxf(a2[j], 0.f);
  *(f32x4*)(out + (((size_t)b * (NL + NP)) + out_off + n) * 64 + c4) = o;
}

extern "C" void kernel_launch(void* const* d_in, const int* in_sizes, int n_in,
                              void* d_out, int out_size, void* d_ws, size_t ws_size,
                              hipStream_t stream)
{
  const float* ligand = (const float*)d_in[0];
  const float* prot   = (const float*)d_in[1];
  const float* dist   = (const float*)d_in[2];
  const float* w_l1   = (const float*)d_in[3];
  const float* b_l1   = (const float*)d_in[4];
  const float* w_l2   = (const float*)d_in[5];
  const float* b_l2   = (const float*)d_in[6];
  const float* w_p1   = (const float*)d_in[7];
  const float* b_p1   = (const float*)d_in[8];
  const float* w_p2   = (const float*)d_in[9];
  const float* b_p2   = (const float*)d_in[10];
  const float* fc11_w = (const float*)d_in[11];
  const float* fc11_b = (const float*)d_in[12];
  const float* fc12_w = (const float*)d_in[13];
  const float* fc12_b = (const float*)d_in[14];
  const float* fc21_w = (const float*)d_in[15];
  const float* fc21_b = (const float*)d_in[16];
  const float* fc22_w = (const float*)d_in[17];
  const float* fc22_b = (const float*)d_in[18];
  float* out = (float*)d_out;

  char* ws = (char*)d_ws;
  size_t off = 0;
  auto alloc = [&](size_t bytes) -> void* {
    void* p = ws + off;
    off += (bytes + 255) & ~(size_t)255;
    return p;
  };
  const size_t L1E = (size_t)B_ * NH * NL * 64;
  const size_t P1E = (size_t)B_ * NH * NP * 64;
  _Float16* l1h = (_Float16*)alloc(L1E * 2);
  _Float16* l1l = (_Float16*)alloc(L1E * 2);
  _Float16* p1h = (_Float16*)alloc(P1E * 2);
  _Float16* p1l = (_Float16*)alloc(P1E * 2);
  _Float16* l2t = (_Float16*)alloc(L1E * 2);
  _Float16* p2t = (_Float16*)alloc(P1E * 2);
  float* mrow  = (float*)alloc((size_t)B_ * NH * NL * 4);
  float* mpart = (float*)alloc((size_t)PSPLIT * B_ * NH * NL * 4);
  float* spart = (float*)alloc((size_t)PSPLIT * B_ * NH * NL * 4);
  float* l3c = (float*)alloc((size_t)B_ * NL * 512 * 4);
  float* p3c = (float*)alloc((size_t)B_ * NP * 512 * 4);
  float* l3p = p3c;   // alias: l3 partials (PSPLIT*B*NL*512*4 = 34 MB) dead before p3 writes p3c

  proj_kernel<<<dim3(NL / 64, NH, B_), 256, 0, stream>>>(ligand, w_l1, b_l1, l1h, l1l, NL, 0);
  proj_kernel<<<dim3(NL / 64, NH, B_), 256, 0, stream>>>(ligand, w_l2, b_l2, l2t, nullptr, NL, 1);
  proj_kernel<<<dim3(NP / 64, NH, B_), 256, 0, stream>>>(prot, w_p1, b_p1, p1h, p1l, NP, 0);
  proj_kernel<<<dim3(NP / 64, NH, B_), 256, 0, stream>>>(prot, w_p2, b_p2, p2t, nullptr, NP, 1);

  flash_l3_kernel<<<dim3(PSPLIT * B_, NL / 16, 2), 256, 0, stream>>>(
      l1h, l1l, p1h, p1l, p2t, dist, l3p, mpart, spart);
  merge_l3_kernel<<<(B_ * NH * NL) / 4, 256, 0, stream>>>(l3p, mpart, spart, l3c, mrow);
  p3_kernel<<<dim3(B_, NP / 16, 2), 256, 0, stream>>>(p1h, p1l, l1h, l1l, l2t, dist,
                                                      mrow, p3c);

  fc_out_kernel<<<(B_ * NL) / 16, 256, 0, stream>>>(l3c, ligand, fc11_w, fc11_b,
                                                    fc12_w, fc12_b, out, NL, 0);
  fc_out_kernel<<<(B_ * NP) / 16, 256, 0, stream>>>(p3c, prot, fc21_w, fc21_b,
                                                    fc22_w, fc22_b, out, NP, NL);
}